// Round 5
// baseline (277.062 us; speedup 1.0000x reference)
//
#include <hip/hip_runtime.h>

#define N_NODES_C 50000
#define FDIM 64
#define EPS_C 1e-5f

#define PARTS 10            // node-space partitions (50000/10 = 5000 exact)
#define NPP 5000            // nodes per partition
#define SLICE (3 * NPP)     // floats per block slice (s, ss, deg) = 15000 -> 60 KB LDS
#define BPERP 48            // blocks per partition; grid = 480, 2 blocks/CU by LDS
#define SCAT_BLK 512

// ---------------------------------------------------------------------------
// Pass A: per-edge partials. Pure dense stream of e (the only big read in the
// stats phase): 16 lanes per edge, float4 each, shfl-reduce within the
// 16-lane group, lane 0 writes float2{sum, sumsq}. partials live in d_out's
// head (overwritten by norm later; stream-ordered so safe).
// ---------------------------------------------------------------------------
__global__ void __launch_bounds__(256)
partial_kernel(const float4* __restrict__ e4, float2* __restrict__ partials,
               int nEdges) {
    const int total = nEdges * 16;
    const int stride = gridDim.x * blockDim.x;   // multiple of 256 -> group-aligned
    for (int idx = blockIdx.x * blockDim.x + threadIdx.x; idx < total; idx += stride) {
        float4 v = e4[idx];
        float sum = (v.x + v.y) + (v.z + v.w);
        float sq  = (v.x * v.x + v.y * v.y) + (v.z * v.z + v.w * v.w);
#pragma unroll
        for (int m = 1; m < 16; m <<= 1) {
            sum += __shfl_xor(sum, m);
            sq  += __shfl_xor(sq,  m);
        }
        if ((idx & 15) == 0) partials[idx >> 4] = make_float2(sum, sq);
    }
}

// ---------------------------------------------------------------------------
// Pass B: scatter the (cache-resident, 19.2 MB) per-edge partials into
// partitioned LDS stats. Unconditional coalesced int4 + 2x float4 loads;
// 3 LDS atomics per in-range edge. No global atomics.
// ---------------------------------------------------------------------------
__global__ void __launch_bounds__(SCAT_BLK)
scatter_kernel(const int* __restrict__ dst, const float2* __restrict__ partials,
               float* __restrict__ acc, int nEdges) {
    __shared__ float sm[SLICE];
    const int tid = threadIdx.x;
    for (int i = tid; i < SLICE; i += SCAT_BLK) sm[i] = 0.0f;
    __syncthreads();

    const int p  = blockIdx.x / BPERP;
    const int b  = blockIdx.x % BPERP;
    const int lo = p * NPP;

    const int step = BPERP * SCAT_BLK * 4;
    for (int i0 = (b * SCAT_BLK + tid) * 4; i0 < nEdges; i0 += step) {
        if (i0 + 3 < nEdges) {
            int4   d4  = *(const int4*)(dst + i0);
            float4 p01 = *(const float4*)(partials + i0);
            float4 p23 = *(const float4*)(partials + i0 + 2);
            unsigned l0 = (unsigned)(d4.x - lo), l1 = (unsigned)(d4.y - lo);
            unsigned l2 = (unsigned)(d4.z - lo), l3 = (unsigned)(d4.w - lo);
            if (l0 < NPP) { atomicAdd(&sm[l0], p01.x); atomicAdd(&sm[NPP + l0], p01.y); atomicAdd(&sm[2 * NPP + l0], 1.f); }
            if (l1 < NPP) { atomicAdd(&sm[l1], p01.z); atomicAdd(&sm[NPP + l1], p01.w); atomicAdd(&sm[2 * NPP + l1], 1.f); }
            if (l2 < NPP) { atomicAdd(&sm[l2], p23.x); atomicAdd(&sm[NPP + l2], p23.y); atomicAdd(&sm[2 * NPP + l2], 1.f); }
            if (l3 < NPP) { atomicAdd(&sm[l3], p23.z); atomicAdd(&sm[NPP + l3], p23.w); atomicAdd(&sm[2 * NPP + l3], 1.f); }
        } else {
            for (int i = i0; i < nEdges; ++i) {
                unsigned l = (unsigned)(dst[i] - lo);
                if (l < NPP) {
                    float2 pq = partials[i];
                    atomicAdd(&sm[l], pq.x);
                    atomicAdd(&sm[NPP + l], pq.y);
                    atomicAdd(&sm[2 * NPP + l], 1.f);
                }
            }
        }
    }
    __syncthreads();
    float* __restrict__ out = acc + (size_t)blockIdx.x * SLICE;
    for (int i = tid; i < SLICE; i += SCAT_BLK) out[i] = sm[i];
}

// ---------------------------------------------------------------------------
// Pass C: sum the BPERP per-block copies of each partition; mean + 1/(std+eps)
// with unbiased (n-1) variance.
// ---------------------------------------------------------------------------
__global__ void __launch_bounds__(256)
reduce_finalize_kernel(const float* __restrict__ acc, float2* __restrict__ stats,
                       int nNodes) {
    int n = blockIdx.x * blockDim.x + threadIdx.x;
    if (n >= nNodes) return;
    int p = n / NPP, local = n - p * NPP;
    const float* base = acc + (size_t)(p * BPERP) * SLICE + local;
    float s = 0.f, q = 0.f, dg = 0.f;
#pragma unroll 8
    for (int bb = 0; bb < BPERP; ++bb) {
        const float* a = base + (size_t)bb * SLICE;
        s  += a[0];
        q  += a[NPP];
        dg += a[2 * NPP];
    }
    float cnt  = dg * (float)FDIM;
    float safe = fmaxf(cnt, 1.0f);
    float mean = s / safe;
    float var  = (q - cnt * mean * mean) / fmaxf(cnt - 1.0f, 1.0f);
    float stdv = sqrtf(fmaxf(var, 0.0f));
    stats[n] = make_float2(mean, 1.0f / (stdv + EPS_C));
}

// ---------------------------------------------------------------------------
// Pass D: out = gamma * (e - mean[dst]) * inv[dst] + beta   (at roofline)
// ---------------------------------------------------------------------------
__global__ void __launch_bounds__(256)
norm_kernel(const float4* __restrict__ e4, const int* __restrict__ dst,
            const float2* __restrict__ stats,
            const float4* __restrict__ gamma4, const float4* __restrict__ beta4,
            float4* __restrict__ out4, int nEdges) {
    const int total = nEdges * 16;
    const int stride = gridDim.x * blockDim.x;
    const int sub = (blockIdx.x * blockDim.x + threadIdx.x) & 15; // stride%16==0
    const float4 g = gamma4[sub];
    const float4 b = beta4[sub];
    for (int idx = blockIdx.x * blockDim.x + threadIdx.x; idx < total; idx += stride) {
        float2 mi = stats[dst[idx >> 4]];
        float4 v  = e4[idx];
        float4 o;
        o.x = g.x * (v.x - mi.x) * mi.y + b.x;
        o.y = g.y * (v.y - mi.x) * mi.y + b.y;
        o.z = g.z * (v.z - mi.x) * mi.y + b.z;
        o.w = g.w * (v.w - mi.x) * mi.y + b.w;
        out4[idx] = o;
    }
}

extern "C" void kernel_launch(void* const* d_in, const int* in_sizes, int n_in,
                              void* d_out, int out_size, void* d_ws, size_t ws_size,
                              hipStream_t stream) {
    const float* e     = (const float*)d_in[0];
    const float* gamma = (const float*)d_in[1];
    const float* beta  = (const float*)d_in[2];
    const int*   dst   = (const int*)d_in[3];
    const int nEdges = in_sizes[3];
    const int nNodes = N_NODES_C;

    // partials scratch lives in d_out's head (12.8 MB of 409.6 MB); it is
    // consumed by scatter_kernel before norm_kernel overwrites all of d_out.
    float2* partials = (float2*)d_out;
    float*  acc      = (float*)d_ws;                                   // [480][SLICE] = 28.8 MB
    float2* stats    = (float2*)(acc + (size_t)PARTS * BPERP * SLICE); // [N], 0.4 MB

    // Pass A: dense per-edge partials (reads e once at full efficiency)
    partial_kernel<<<2048, 256, 0, stream>>>((const float4*)e, partials, nEdges);

    // Pass B: cache-resident scatter into partitioned LDS (writes all of acc)
    scatter_kernel<<<PARTS * BPERP, SCAT_BLK, 0, stream>>>(dst, partials, acc, nEdges);

    // Pass C: cross-block reduce + finalize
    reduce_finalize_kernel<<<(nNodes + 255) / 256, 256, 0, stream>>>(acc, stats, nNodes);

    // Pass D: normalize (roofline-bound)
    norm_kernel<<<2048, 256, 0, stream>>>(
        (const float4*)e, dst, stats,
        (const float4*)gamma, (const float4*)beta,
        (float4*)d_out, nEdges);
}

// Round 7
// 270.772 us; speedup vs baseline: 1.0232x; 1.0232x over previous
//
#include <hip/hip_runtime.h>

#define N_NODES_C 50000
#define FDIM 64
#define EPS_C 1e-5f

#define PARTS 16            // 50000/16 = 3125 exact
#define NPP 3125
#define SLICE (3 * NPP)     // 9375 floats = 37.5 KB LDS -> 4 blocks/CU
#define BPERP 64            // %8==0: all 16 readers of slice b share XCD b%8
#define SCAT_BLK 512
#define SCAT_GRID (PARTS * BPERP)

// one edge: conditional LDS-atomic triple
#define EDGE_ACC(D, SV, QV)                                            \
    { unsigned l_ = (unsigned)((D) - lo);                              \
      if (l_ < NPP) { atomicAdd(&sm[l_], (SV));                        \
                      atomicAdd(&sm[NPP + l_], (QV));                  \
                      atomicAdd(&sm[2 * NPP + l_], 1.0f); } }

// ---------------------------------------------------------------------------
// Pass A: per-edge partials. Dense stream of e: 16 lanes/edge, float4 each,
// shfl-reduce in the 16-lane group, lane 0 writes float2{sum, sumsq}.
// ---------------------------------------------------------------------------
__global__ void __launch_bounds__(256)
partial_kernel(const float4* __restrict__ e4, float2* __restrict__ partials,
               int nEdges) {
    const int total = nEdges * 16;
    const int stride = gridDim.x * blockDim.x;   // %16==0 -> groups aligned
    for (int idx = blockIdx.x * blockDim.x + threadIdx.x; idx < total; idx += stride) {
        float4 v = e4[idx];
        float sum = (v.x + v.y) + (v.z + v.w);
        float sq  = (v.x * v.x + v.y * v.y) + (v.z * v.z + v.w * v.w);
#pragma unroll
        for (int m = 1; m < 16; m <<= 1) {
            sum += __shfl_xor(sum, m);
            sq  += __shfl_xor(sq,  m);
        }
        if ((idx & 15) == 0) partials[idx >> 4] = make_float2(sum, sq);
    }
}

// ---------------------------------------------------------------------------
// Pass B: scatter the cache-resident partials into partitioned LDS stats.
// blockIdx = p*BPERP + b: partition p scans edge-slice b; all 16 partitions
// of a slice land on the same XCD (BPERP%8==0) so dst+partials are L2-shared.
// 4 blocks/CU (37.5 KB LDS, 64-VGPR cap) = 32 waves/CU.
// ---------------------------------------------------------------------------
__global__ void __launch_bounds__(SCAT_BLK, 8)
scatter_kernel(const int* __restrict__ dst, const float2* __restrict__ partials,
               float* __restrict__ acc, int nEdges) {
    __shared__ float sm[SLICE];
    const int tid = threadIdx.x;
    for (int i = tid; i < SLICE; i += SCAT_BLK) sm[i] = 0.0f;
    __syncthreads();

    const int p  = blockIdx.x / BPERP;
    const int b  = blockIdx.x % BPERP;
    const int lo = p * NPP;

    const int step = BPERP * SCAT_BLK * 8;      // 2,097,152 edges per sweep? no: 64*512*8 = 262144
    for (int i0 = (b * SCAT_BLK + tid) * 8; i0 < nEdges; i0 += step) {
        if (i0 + 7 < nEdges) {
            int4   da = *(const int4*)(dst + i0);
            int4   db = *(const int4*)(dst + i0 + 4);
            float4 p0 = *(const float4*)(partials + i0);
            float4 p1 = *(const float4*)(partials + i0 + 2);
            float4 p2 = *(const float4*)(partials + i0 + 4);
            float4 p3 = *(const float4*)(partials + i0 + 6);
            EDGE_ACC(da.x, p0.x, p0.y); EDGE_ACC(da.y, p0.z, p0.w);
            EDGE_ACC(da.z, p1.x, p1.y); EDGE_ACC(da.w, p1.z, p1.w);
            EDGE_ACC(db.x, p2.x, p2.y); EDGE_ACC(db.y, p2.z, p2.w);
            EDGE_ACC(db.z, p3.x, p3.y); EDGE_ACC(db.w, p3.z, p3.w);
        } else {
            for (int i = i0; i < nEdges; ++i) {
                float2 pq = partials[i];
                EDGE_ACC(dst[i], pq.x, pq.y);
            }
        }
    }
    __syncthreads();
    float* __restrict__ outp = acc + (size_t)blockIdx.x * SLICE;
    for (int i = tid; i < SLICE; i += SCAT_BLK) outp[i] = sm[i];
}

// ---------------------------------------------------------------------------
// Pass C: sum the BPERP per-block copies; mean + 1/(std+eps), unbiased (n-1).
// ---------------------------------------------------------------------------
__global__ void __launch_bounds__(256)
reduce_finalize_kernel(const float* __restrict__ acc, float2* __restrict__ stats,
                       int nNodes) {
    int n = blockIdx.x * blockDim.x + threadIdx.x;
    if (n >= nNodes) return;
    int p = n / NPP, local = n - p * NPP;
    const float* bptr = acc + (size_t)(p * BPERP) * SLICE + local;
    float s = 0.f, q = 0.f, dg = 0.f;
#pragma unroll 8
    for (int bb = 0; bb < BPERP; ++bb, bptr += SLICE) {
        s  += bptr[0];
        q  += bptr[NPP];
        dg += bptr[2 * NPP];
    }
    float cnt  = dg * (float)FDIM;
    float safe = fmaxf(cnt, 1.0f);
    float mean = s / safe;
    float var  = (q - cnt * mean * mean) / fmaxf(cnt - 1.0f, 1.0f);
    float stdv = sqrtf(fmaxf(var, 0.0f));
    stats[n] = make_float2(mean, 1.0f / (stdv + EPS_C));
}

// ---------------------------------------------------------------------------
// Pass D: normalize, iterating chunks in REVERSE so the re-read of e starts
// with the tail that partial_kernel left resident in the 256 MB L3.
// ---------------------------------------------------------------------------
__global__ void __launch_bounds__(256)
norm_kernel(const float4* __restrict__ e4, const int* __restrict__ dst,
            const float2* __restrict__ stats,
            const float4* __restrict__ gamma4, const float4* __restrict__ beta4,
            float4* __restrict__ out4, int nEdges) {
    const int total  = nEdges * 16;
    const int stride = gridDim.x * blockDim.x;   // %16==0
    const int gtid   = blockIdx.x * blockDim.x + threadIdx.x;
    const int sub    = gtid & 15;
    const float4 g = gamma4[sub];
    const float4 b = beta4[sub];
    const int nIter = (total + stride - 1) / stride;
    for (int it = nIter - 1; it >= 0; --it) {
        int idx = it * stride + gtid;
        if (idx >= total) continue;
        float2 mi = stats[dst[idx >> 4]];
        float4 v  = e4[idx];
        float4 o;
        o.x = g.x * (v.x - mi.x) * mi.y + b.x;
        o.y = g.y * (v.y - mi.x) * mi.y + b.y;
        o.z = g.z * (v.z - mi.x) * mi.y + b.z;
        o.w = g.w * (v.w - mi.x) * mi.y + b.w;
        out4[idx] = o;
    }
}

extern "C" void kernel_launch(void* const* d_in, const int* in_sizes, int n_in,
                              void* d_out, int out_size, void* d_ws, size_t ws_size,
                              hipStream_t stream) {
    const float* e     = (const float*)d_in[0];
    const float* gamma = (const float*)d_in[1];
    const float* beta  = (const float*)d_in[2];
    const int*   dst   = (const int*)d_in[3];
    const int nEdges = in_sizes[3];
    const int nNodes = N_NODES_C;

    // d_ws layout (all regions fully overwritten every call -> no memset):
    //   acc      [SCAT_GRID][SLICE] = 38.4 MB
    //   stats    [N] float2         =  0.4 MB
    //   partials [E] float2         = 12.8 MB
    float*  acc      = (float*)d_ws;
    float2* stats    = (float2*)(acc + (size_t)SCAT_GRID * SLICE);
    float2* partials = stats + nNodes;

    partial_kernel<<<2048, 256, 0, stream>>>((const float4*)e, partials, nEdges);
    scatter_kernel<<<SCAT_GRID, SCAT_BLK, 0, stream>>>(dst, partials, acc, nEdges);
    reduce_finalize_kernel<<<(nNodes + 255) / 256, 256, 0, stream>>>(acc, stats, nNodes);
    norm_kernel<<<2048, 256, 0, stream>>>(
        (const float4*)e, dst, stats,
        (const float4*)gamma, (const float4*)beta,
        (float4*)d_out, nEdges);
}

// Round 8
// 244.454 us; speedup vs baseline: 1.1334x; 1.1077x over previous
//
#include <hip/hip_runtime.h>

#define N_NODES_C 50000
#define FDIM 64
#define EPS_C 1e-5f

#define PARTS 16            // 50000/16 = 3125 exact
#define NPP 3125
#define SLICE (3 * NPP)     // 9375 floats = 37.5 KB LDS
#define BPERP 48            // %8==0: all 16 readers of slice b share XCD b%8
#define SCAT_BLK 512
#define SCAT_GRID (PARTS * BPERP)   // 768 = 3 blocks/CU (slack vs 4/CU cap)

typedef float vfloat4 __attribute__((ext_vector_type(4)));

__device__ __forceinline__ void nt_store_f4(float4* p, float x, float y, float z, float w) {
    vfloat4 v = { x, y, z, w };
    __builtin_nontemporal_store(v, (vfloat4*)p);
}

// one edge: conditional LDS-atomic triple
#define EDGE_ACC(D, SV, QV)                                            \
    { unsigned l_ = (unsigned)((D) - lo);                              \
      if (l_ < NPP) { atomicAdd(&sm[l_], (SV));                        \
                      atomicAdd(&sm[NPP + l_], (QV));                  \
                      atomicAdd(&sm[2 * NPP + l_], 1.0f); } }

// ---------------------------------------------------------------------------
// Pass A: per-edge partials. Dense stream of e (normal loads -> e allocates
// in L3 for norm's re-read); nt-store the partials (no reuse pollution).
// ---------------------------------------------------------------------------
__global__ void __launch_bounds__(256)
partial_kernel(const float4* __restrict__ e4, float2* __restrict__ partials,
               int nEdges) {
    const int total = nEdges * 16;
    const int stride = gridDim.x * blockDim.x;   // %16==0 -> groups aligned
    for (int idx = blockIdx.x * blockDim.x + threadIdx.x; idx < total; idx += stride) {
        float4 v = e4[idx];
        float sum = (v.x + v.y) + (v.z + v.w);
        float sq  = (v.x * v.x + v.y * v.y) + (v.z * v.z + v.w * v.w);
#pragma unroll
        for (int m = 1; m < 16; m <<= 1) {
            sum += __shfl_xor(sum, m);
            sq  += __shfl_xor(sq,  m);
        }
        if ((idx & 15) == 0) {
            unsigned long long bits;
            float2 pq = make_float2(sum, sq);
            __builtin_memcpy(&bits, &pq, 8);
            __builtin_nontemporal_store(bits, (unsigned long long*)(partials + (idx >> 4)));
        }
    }
}

// ---------------------------------------------------------------------------
// Pass B: scatter cache-resident partials into partitioned LDS stats.
// blockIdx = p*BPERP + b; BPERP%8==0 -> XCD(bid)=b%8 under round-robin
// dispatch: each XCD holds 6 slices (2.4 MB dst+partials) in its L2, read by
// all 16 partitions. 3 blocks/CU (scheduling slack), 85-VGPR budget.
// ---------------------------------------------------------------------------
__global__ void __launch_bounds__(SCAT_BLK, 6)
scatter_kernel(const int* __restrict__ dst, const float2* __restrict__ partials,
               float* __restrict__ acc, int nEdges) {
    __shared__ float sm[SLICE];
    const int tid = threadIdx.x;
    for (int i = tid; i < SLICE; i += SCAT_BLK) sm[i] = 0.0f;
    __syncthreads();

    const int p  = blockIdx.x / BPERP;
    const int b  = blockIdx.x % BPERP;
    const int lo = p * NPP;

    const int step = BPERP * SCAT_BLK * 4;
    for (int i0 = (b * SCAT_BLK + tid) * 4; i0 < nEdges; i0 += step) {
        if (i0 + 3 < nEdges) {
            int4   d4  = *(const int4*)(dst + i0);
            float4 p01 = *(const float4*)(partials + i0);
            float4 p23 = *(const float4*)(partials + i0 + 2);
            EDGE_ACC(d4.x, p01.x, p01.y); EDGE_ACC(d4.y, p01.z, p01.w);
            EDGE_ACC(d4.z, p23.x, p23.y); EDGE_ACC(d4.w, p23.z, p23.w);
        } else {
            for (int i = i0; i < nEdges; ++i) {
                float2 pq = partials[i];
                EDGE_ACC(dst[i], pq.x, pq.y);
            }
        }
    }
    __syncthreads();
    float* __restrict__ outp = acc + (size_t)blockIdx.x * SLICE;
    for (int i = tid; i < SLICE; i += SCAT_BLK) {
        __builtin_nontemporal_store(sm[i], outp + i);   // no L3 pollution
    }
}

// ---------------------------------------------------------------------------
// Pass C: sum the BPERP per-block copies; mean + 1/(std+eps), unbiased (n-1).
// ---------------------------------------------------------------------------
__global__ void __launch_bounds__(256)
reduce_finalize_kernel(const float* __restrict__ acc, float2* __restrict__ stats,
                       int nNodes) {
    int n = blockIdx.x * blockDim.x + threadIdx.x;
    if (n >= nNodes) return;
    int p = n / NPP, local = n - p * NPP;
    const float* bptr = acc + (size_t)(p * BPERP) * SLICE + local;
    float s = 0.f, q = 0.f, dg = 0.f;
#pragma unroll 8
    for (int bb = 0; bb < BPERP; ++bb, bptr += SLICE) {
        s  += bptr[0];
        q  += bptr[NPP];
        dg += bptr[2 * NPP];
    }
    float cnt  = dg * (float)FDIM;
    float safe = fmaxf(cnt, 1.0f);
    float mean = s / safe;
    float var  = (q - cnt * mean * mean) / fmaxf(cnt - 1.0f, 1.0f);
    float stdv = sqrtf(fmaxf(var, 0.0f));
    stats[n] = make_float2(mean, 1.0f / (stdv + EPS_C));
}

// ---------------------------------------------------------------------------
// Pass D: normalize. Reverse iteration order (read e's L3-resident tail
// first) + nt-stores for out (keep out's 410 MB from evicting e in L3).
// ---------------------------------------------------------------------------
__global__ void __launch_bounds__(256)
norm_kernel(const float4* __restrict__ e4, const int* __restrict__ dst,
            const float2* __restrict__ stats,
            const float4* __restrict__ gamma4, const float4* __restrict__ beta4,
            float4* __restrict__ out4, int nEdges) {
    const int total  = nEdges * 16;
    const int stride = gridDim.x * blockDim.x;   // %16==0
    const int gtid   = blockIdx.x * blockDim.x + threadIdx.x;
    const int sub    = gtid & 15;
    const float4 g = gamma4[sub];
    const float4 b = beta4[sub];
    const int nIter = (total + stride - 1) / stride;
    for (int it = nIter - 1; it >= 0; --it) {
        int idx = it * stride + gtid;
        if (idx >= total) continue;
        float2 mi = stats[dst[idx >> 4]];
        float4 v  = e4[idx];
        nt_store_f4(out4 + idx,
                    g.x * (v.x - mi.x) * mi.y + b.x,
                    g.y * (v.y - mi.x) * mi.y + b.y,
                    g.z * (v.z - mi.x) * mi.y + b.z,
                    g.w * (v.w - mi.x) * mi.y + b.w);
    }
}

extern "C" void kernel_launch(void* const* d_in, const int* in_sizes, int n_in,
                              void* d_out, int out_size, void* d_ws, size_t ws_size,
                              hipStream_t stream) {
    const float* e     = (const float*)d_in[0];
    const float* gamma = (const float*)d_in[1];
    const float* beta  = (const float*)d_in[2];
    const int*   dst   = (const int*)d_in[3];
    const int nEdges = in_sizes[3];
    const int nNodes = N_NODES_C;

    // d_ws layout (all regions fully overwritten every call -> no memset):
    //   acc      [SCAT_GRID][SLICE] = 28.8 MB
    //   stats    [N] float2         =  0.4 MB
    //   partials [E] float2         = 12.8 MB
    float*  acc      = (float*)d_ws;
    float2* stats    = (float2*)(acc + (size_t)SCAT_GRID * SLICE);
    float2* partials = stats + nNodes;

    partial_kernel<<<2048, 256, 0, stream>>>((const float4*)e, partials, nEdges);
    scatter_kernel<<<SCAT_GRID, SCAT_BLK, 0, stream>>>(dst, partials, acc, nEdges);
    reduce_finalize_kernel<<<(nNodes + 255) / 256, 256, 0, stream>>>(acc, stats, nNodes);
    norm_kernel<<<2048, 256, 0, stream>>>(
        (const float4*)e, dst, stats,
        (const float4*)gamma, (const float4*)beta,
        (float4*)d_out, nEdges);
}